// Round 7
// baseline (350.899 us; speedup 1.0000x reference)
//
#include <hip/hip_runtime.h>

#define N_NODES 20000
#define N_EDGES 320000
#define NFEAT 14
#define DIM 256

typedef short bf16x8 __attribute__((ext_vector_type(8)));
typedef float f32x4 __attribute__((ext_vector_type(4)));

__device__ __forceinline__ float b2f(unsigned short u) {
    union { unsigned int u; float f; } v; v.u = ((unsigned int)u) << 16; return v.f;
}
__device__ __forceinline__ unsigned short f2b(float f) {
    union { float f; unsigned int u; } v; v.f = f;
    unsigned int r = v.u + 0x7fffu + ((v.u >> 16) & 1u);
    return (unsigned short)(r >> 16);
}

// ---------------- CSR build ----------------

__global__ __launch_bounds__(256) void k_degree(const int* __restrict__ ei, int* __restrict__ cnt) {
    int e = blockIdx.x * 256 + threadIdx.x;
    if (e < N_EDGES) atomicAdd(&cnt[ei[N_EDGES + e]], 1);
}

// Wave-aggregated bump allocation (CSR row placement order is irrelevant:
// only row_ptr/deg pairs are consumed downstream).
__global__ __launch_bounds__(256) void k_alloc(const int* __restrict__ cnt,
                                               int* __restrict__ total,
                                               int* __restrict__ row_ptr,
                                               int* __restrict__ cursor) {
    int i = blockIdx.x * 256 + threadIdx.x;
    int lane = threadIdx.x & 63;
    int deg = (i < N_NODES) ? cnt[i] : 0;
    int s = deg;
    for (int o = 1; o < 64; o <<= 1) { int t = __shfl_up(s, o); if (lane >= o) s += t; }
    int wsum = __shfl(s, 63);
    int base = 0;
    if (lane == 63) base = atomicAdd(total, wsum);
    base = __shfl(base, 63);
    int excl = base + s - deg;
    if (i < N_NODES) { row_ptr[i] = excl; cursor[i] = excl; }
}

__global__ __launch_bounds__(256) void k_fill(const int* __restrict__ ei, const float* __restrict__ ew,
                                              int* __restrict__ cursor,
                                              int* __restrict__ csr_src, float* __restrict__ csr_w) {
    int e = blockIdx.x * 256 + threadIdx.x;
    if (e < N_EDGES) {
        int d = ei[N_EDGES + e];
        int p = atomicAdd(&cursor[d], 1);
        csr_src[p] = ei[e];
        csr_w[p] = ew[e];
    }
}

// ---------------- weight staging (coalesced read + LDS transpose) ----------------
// Per 256x256 part p: Wstage[s][c][j] = bf16( W[k = koff + s*32 + j][c] ), s<8, c<256, j<32.
// Grid: 56 blocks = part*8 + s.

__global__ __launch_bounds__(256) void k_wstage(
    const float* __restrict__ W2r, const float* __restrict__ W2o,
    const float* __restrict__ W3r, const float* __restrict__ W3o,
    const float* __restrict__ Wl, unsigned short* __restrict__ out) {
    __shared__ unsigned short tb[256][33];   // [c][j], pad 32->33
    int part = blockIdx.x >> 3, s = blockIdx.x & 7;
    int tid = threadIdx.x;
    const float* W; int koff = 0;
    switch (part) {
        case 0: W = W2r; break;
        case 1: W = W2o; break;
        case 2: W = W3r; break;
        case 3: W = W3o; break;
        default: W = Wl; koff = (part - 4) * 256; break;
    }
#pragma unroll 4
    for (int j = 0; j < 32; ++j) {
        tb[tid][j] = f2b(W[(size_t)(koff + s * 32 + j) * 256 + tid]);   // coalesced 1KB row
    }
    __syncthreads();
    unsigned short* dst = out + (size_t)part * 65536 + (size_t)s * 8192;
#pragma unroll 4
    for (int i = 0; i < 32; ++i) {
        int flat = i * 256 + tid;                 // = c*32 + j
        dst[flat] = tb[flat >> 5][flat & 31];     // coalesced write, ~2-way LDS read
    }
}

// ---------------- Layer 1 (K=14, fused, fp32 math, bf16 out) ----------------
// Grid 625, 32 nodes/block (4 waves x 8 sequential nodes).
// Lane layout: lane = esub*16 + k (4 edges in parallel, k=feature), reduce = 2 shfl_xor.

__global__ __launch_bounds__(256) void k_layer1(
    const float* __restrict__ x, const int* __restrict__ row_ptr, const int* __restrict__ cnt,
    const int* __restrict__ csr_src, const float* __restrict__ csr_w,
    const float* __restrict__ Wrel, const float* __restrict__ brel, const float* __restrict__ Wroot,
    unsigned short* __restrict__ x1b) {
    __shared__ float sWrel[NFEAT][DIM];
    __shared__ float sWroot[NFEAT][DIM];
    __shared__ float sb[DIM];
    int tid = threadIdx.x;
    for (int i = tid; i < NFEAT * DIM; i += 256) {
        (&sWrel[0][0])[i] = Wrel[i];
        (&sWroot[0][0])[i] = Wroot[i];
    }
    if (tid < DIM) sb[tid] = brel[tid];
    __syncthreads();

    int wv = tid >> 6, lane = tid & 63;
    int esub = lane >> 4, k = lane & 15;
    bool kval = (k < NFEAT);

    for (int n8 = 0; n8 < 8; ++n8) {
        int node = blockIdx.x * 32 + n8 * 4 + wv;
        int start = row_ptr[node], deg = cnt[node];
        int end = start + deg;

        float acc = 0.f;
        for (int e0 = start; e0 < end; e0 += 4) {
            int e = e0 + esub;
            if (e < end && kval) {
                int s = csr_src[e];
                acc += x[(size_t)s * NFEAT + k] * csr_w[e];
            }
        }
        acc += __shfl_xor(acc, 16);
        acc += __shfl_xor(acc, 32);
        float macc = acc / fmaxf((float)deg, 1.f);

        float av[NFEAT], xr[NFEAT];
#pragma unroll
        for (int k2 = 0; k2 < NFEAT; ++k2) av[k2] = __shfl(macc, k2);
#pragma unroll
        for (int k2 = 0; k2 < NFEAT; ++k2) xr[k2] = x[(size_t)node * NFEAT + k2];

#pragma unroll
        for (int j = 0; j < 4; ++j) {
            int d = lane + 64 * j;
            float o = sb[d];
#pragma unroll
            for (int k2 = 0; k2 < NFEAT; ++k2)
                o += av[k2] * sWrel[k2][d] + xr[k2] * sWroot[k2][d];
            x1b[(size_t)node * DIM + d] = f2b(fmaxf(o, 0.f));
        }
    }
}

// ---------------- SpMM mean aggregation (bf16 in/out, fp32 accum) ----------------

__global__ __launch_bounds__(256) void k_spmm_mean(
    const unsigned short* __restrict__ xin, const int* __restrict__ row_ptr,
    const int* __restrict__ cnt, const int* __restrict__ csr_src,
    const float* __restrict__ csr_w, unsigned short* __restrict__ meanb) {
    int wv = threadIdx.x >> 6, lane = threadIdx.x & 63;
    int node = blockIdx.x * 4 + wv;
    int start = row_ptr[node], deg = cnt[node];
    float a0 = 0.f, a1 = 0.f, a2 = 0.f, a3 = 0.f;
    for (int e = start; e < start + deg; ++e) {
        int s = csr_src[e];
        float w = csr_w[e];
        ushort4 v = *(const ushort4*)(xin + (size_t)s * DIM + lane * 4);
        a0 += b2f(v.x) * w; a1 += b2f(v.y) * w; a2 += b2f(v.z) * w; a3 += b2f(v.w) * w;
    }
    float inv = 1.f / fmaxf((float)deg, 1.f);
    ushort4 o;
    o.x = f2b(a0 * inv); o.y = f2b(a1 * inv); o.z = f2b(a2 * inv); o.w = f2b(a3 * inv);
    *(ushort4*)(meanb + (size_t)node * DIM + lane * 4) = o;
}

// ---------------- bf16 MFMA multi-part GEMM ----------------
// C[M,256] = act( sum_p A_p[M,256] @ B_p[256,256] + bias ), A_p bf16, B_p in Wstage layout.
// Block: 256 thr = 4 waves; 32 rows x 256 cols per block. 20000 = 625*32 -> no row guards.

__global__ __launch_bounds__(256) void k_gemm_mfma(
    const unsigned short* __restrict__ A0, const unsigned short* __restrict__ A1,
    const unsigned short* __restrict__ A2,
    const unsigned short* __restrict__ B0, const unsigned short* __restrict__ B1,
    const unsigned short* __restrict__ B2,
    int nparts, const float* __restrict__ bias,
    unsigned short* __restrict__ outb, float* __restrict__ outf, int do_relu) {
    __shared__ __align__(16) unsigned short Bs[256][40];   // pad 32->40: <=2-way bank conflict
    int t = threadIdx.x;
    int l = t & 63, wv = t >> 6;
    int rowPanel = wv >> 1, colPanel = wv & 1;
    int row0 = blockIdx.x * 32;
    int lr = l & 15, kg = l >> 4;
    int row_a = row0 + rowPanel * 16 + lr;

    f32x4 acc[8];
#pragma unroll
    for (int i = 0; i < 8; i++) acc[i] = (f32x4){0.f, 0.f, 0.f, 0.f};

    for (int p = 0; p < nparts; ++p) {
        const unsigned short* A = (p == 0) ? A0 : (p == 1) ? A1 : A2;
        const unsigned short* B = (p == 0) ? B0 : (p == 1) ? B1 : B2;
        for (int s = 0; s < 8; ++s) {
            const int4* src = (const int4*)(B + (size_t)s * 8192 + (size_t)t * 32);
            int4 v0 = src[0], v1 = src[1], v2 = src[2], v3 = src[3];
            *(int4*)&Bs[t][0]  = v0;
            *(int4*)&Bs[t][8]  = v1;
            *(int4*)&Bs[t][16] = v2;
            *(int4*)&Bs[t][24] = v3;
            __syncthreads();
            bf16x8 a = *(const bf16x8*)(A + (size_t)row_a * DIM + s * 32 + kg * 8);
#pragma unroll
            for (int ct = 0; ct < 8; ++ct) {
                int col = colPanel * 128 + ct * 16 + lr;
                bf16x8 b = *(const bf16x8*)&Bs[col][kg * 8];
                acc[ct] = __builtin_amdgcn_mfma_f32_16x16x32_bf16(a, b, acc[ct], 0, 0, 0);
            }
            __syncthreads();
        }
    }

#pragma unroll
    for (int ct = 0; ct < 8; ++ct) {
        int col = colPanel * 128 + ct * 16 + lr;
        float bv = bias[col];
#pragma unroll
        for (int r = 0; r < 4; ++r) {
            int row = row0 + rowPanel * 16 + kg * 4 + r;
            float v = acc[ct][r] + bv;
            if (do_relu) v = fmaxf(v, 0.f);
            if (outb) outb[(size_t)row * DIM + col] = f2b(v);
            else      outf[(size_t)row * DIM + col] = v;
        }
    }
}

// ---------------- host ----------------

extern "C" void kernel_launch(void* const* d_in, const int* in_sizes, int n_in,
                              void* d_out, int out_size, void* d_ws, size_t ws_size,
                              hipStream_t stream) {
    (void)in_sizes; (void)n_in; (void)out_size; (void)ws_size;
    const float* x       = (const float*)d_in[0];
    const int*   ei      = (const int*)d_in[1];
    const float* ew      = (const float*)d_in[2];
    const float* W1_rel  = (const float*)d_in[3];
    const float* b1      = (const float*)d_in[4];
    const float* W1_root = (const float*)d_in[5];
    const float* W2_rel  = (const float*)d_in[6];
    const float* b2      = (const float*)d_in[7];
    const float* W2_root = (const float*)d_in[8];
    const float* W3_rel  = (const float*)d_in[9];
    const float* b3      = (const float*)d_in[10];
    const float* W3_root = (const float*)d_in[11];
    const float* W_lin   = (const float*)d_in[12];
    const float* b_lin   = (const float*)d_in[13];
    float* out = (float*)d_out;

    char* ws = (char*)d_ws;
    size_t off = 0;
    auto alloc = [&](size_t bytes) -> void* {
        off = (off + 255) & ~(size_t)255;
        void* p = ws + off;
        off += bytes;
        return p;
    };
    int*   cnt     = (int*)alloc((size_t)(N_NODES + 1) * 4);   // +1: bump counter
    int*   row_ptr = (int*)alloc((size_t)N_NODES * 4);
    int*   cursor  = (int*)alloc((size_t)N_NODES * 4);
    int*   csr_src = (int*)alloc((size_t)N_EDGES * 4);
    float* csr_w   = (float*)alloc((size_t)N_EDGES * 4);
    unsigned short* wst   = (unsigned short*)alloc((size_t)7 * 65536 * 2);
    unsigned short* meanb = (unsigned short*)alloc((size_t)N_NODES * DIM * 2);
    unsigned short* x1b   = (unsigned short*)alloc((size_t)N_NODES * DIM * 2);
    unsigned short* x2b   = (unsigned short*)alloc((size_t)N_NODES * DIM * 2);
    unsigned short* x3b   = (unsigned short*)alloc((size_t)N_NODES * DIM * 2);
    int* total = cnt + N_NODES;

    hipMemsetAsync(cnt, 0, (size_t)(N_NODES + 1) * 4, stream);

    int eblocks = (N_EDGES + 255) / 256;
    k_degree<<<eblocks, 256, 0, stream>>>(ei, cnt);
    k_alloc<<<(N_NODES + 255) / 256, 256, 0, stream>>>(cnt, total, row_ptr, cursor);
    k_fill<<<eblocks, 256, 0, stream>>>(ei, ew, cursor, csr_src, csr_w);

    k_wstage<<<56, 256, 0, stream>>>(W2_rel, W2_root, W3_rel, W3_root, W_lin, wst);

    k_layer1<<<N_NODES / 32, 256, 0, stream>>>(x, row_ptr, cnt, csr_src, csr_w,
                                               W1_rel, b1, W1_root, x1b);

    const int ggrid = N_NODES / 32;   // 625

    // layer 2: relu(mean(x1)@W2_rel + x1@W2_root + b2) -> x2b
    k_spmm_mean<<<N_NODES / 4, 256, 0, stream>>>(x1b, row_ptr, cnt, csr_src, csr_w, meanb);
    k_gemm_mfma<<<ggrid, 256, 0, stream>>>(meanb, x1b, nullptr,
                                           wst, wst + 65536, nullptr,
                                           2, b2, x2b, nullptr, 1);

    // layer 3
    k_spmm_mean<<<N_NODES / 4, 256, 0, stream>>>(x2b, row_ptr, cnt, csr_src, csr_w, meanb);
    k_gemm_mfma<<<ggrid, 256, 0, stream>>>(meanb, x2b, nullptr,
                                           wst + 2 * 65536, wst + 3 * 65536, nullptr,
                                           2, b3, x3b, nullptr, 1);

    // final: concat(x1,x2,x3) @ W_lin + b_lin -> fp32 out
    k_gemm_mfma<<<ggrid, 256, 0, stream>>>(x1b, x2b, x3b,
                                           wst + 4 * 65536, wst + 5 * 65536, wst + 6 * 65536,
                                           3, b_lin, nullptr, out, 0);
}

// Round 11
// 287.776 us; speedup vs baseline: 1.2193x; 1.2193x over previous
//
#include <hip/hip_runtime.h>

#define N_NODES 20000
#define N_EDGES 320000
#define NFEAT 14
#define DIM 256

typedef short bf16x8 __attribute__((ext_vector_type(8)));
typedef float f32x4 __attribute__((ext_vector_type(4)));

__device__ __forceinline__ float b2f(unsigned short u) {
    union { unsigned int u; float f; } v; v.u = ((unsigned int)u) << 16; return v.f;
}
__device__ __forceinline__ unsigned short f2b(float f) {
    union { float f; unsigned int u; } v; v.f = f;
    unsigned int r = v.u + 0x7fffu + ((v.u >> 16) & 1u);
    return (unsigned short)(r >> 16);
}

// ---------------- CSR build ----------------

__global__ __launch_bounds__(256) void k_degree(const int* __restrict__ ei, int* __restrict__ cnt) {
    int e = blockIdx.x * 256 + threadIdx.x;
    if (e < N_EDGES) atomicAdd(&cnt[ei[N_EDGES + e]], 1);
}

__global__ __launch_bounds__(256) void k_alloc(const int* __restrict__ cnt,
                                               int* __restrict__ total,
                                               int* __restrict__ row_ptr,
                                               int* __restrict__ cursor) {
    int i = blockIdx.x * 256 + threadIdx.x;
    int lane = threadIdx.x & 63;
    int deg = (i < N_NODES) ? cnt[i] : 0;
    int s = deg;
    for (int o = 1; o < 64; o <<= 1) { int t = __shfl_up(s, o); if (lane >= o) s += t; }
    int wsum = __shfl(s, 63);
    int base = 0;
    if (lane == 63) base = atomicAdd(total, wsum);
    base = __shfl(base, 63);
    int excl = base + s - deg;
    if (i < N_NODES) { row_ptr[i] = excl; cursor[i] = excl; }
}

__global__ __launch_bounds__(256) void k_fill(const int* __restrict__ ei, const float* __restrict__ ew,
                                              int* __restrict__ cursor,
                                              int* __restrict__ csr_src, float* __restrict__ csr_w) {
    int e = blockIdx.x * 256 + threadIdx.x;
    if (e < N_EDGES) {
        int d = ei[N_EDGES + e];
        int p = atomicAdd(&cursor[d], 1);
        csr_src[p] = ei[e];
        csr_w[p] = ew[e];
    }
}

// ---------------- weight staging (coalesced read + LDS transpose) ----------------

__global__ __launch_bounds__(256) void k_wstage(
    const float* __restrict__ W2r, const float* __restrict__ W2o,
    const float* __restrict__ W3r, const float* __restrict__ W3o,
    const float* __restrict__ Wl, unsigned short* __restrict__ out) {
    __shared__ unsigned short tb[256][33];
    int part = blockIdx.x >> 3, s = blockIdx.x & 7;
    int tid = threadIdx.x;
    const float* W; int koff = 0;
    switch (part) {
        case 0: W = W2r; break;
        case 1: W = W2o; break;
        case 2: W = W3r; break;
        case 3: W = W3o; break;
        default: W = Wl; koff = (part - 4) * 256; break;
    }
#pragma unroll 4
    for (int j = 0; j < 32; ++j) {
        tb[tid][j] = f2b(W[(size_t)(koff + s * 32 + j) * 256 + tid]);
    }
    __syncthreads();
    unsigned short* dst = out + (size_t)part * 65536 + (size_t)s * 8192;
#pragma unroll 4
    for (int i = 0; i < 32; ++i) {
        int flat = i * 256 + tid;
        dst[flat] = tb[flat >> 5][flat & 31];
    }
}

// ---------------- Layer-1 aggregation: mean over neighbors of x [N,14] ----------------
// One node per 16-lane group; 20000 nodes all in flight (grid 1250).
// csr entries prefetched 4-wide -> 4 independent gather streams per group.

__global__ __launch_bounds__(256) void k_agg14(
    const float* __restrict__ x, const int* __restrict__ row_ptr, const int* __restrict__ cnt,
    const int* __restrict__ csr_src, const float* __restrict__ csr_w,
    float* __restrict__ agg) {
    int t = blockIdx.x * 256 + threadIdx.x;   // 320000 threads exactly
    int node = t >> 4, k = t & 15;
    int start = row_ptr[node], deg = cnt[node], end = start + deg;
    bool kv = (k < NFEAT);
    float acc = 0.f;
    for (int e0 = start; e0 < end; e0 += 4) {
        int rem = end - e0;
        int s0 = csr_src[e0];                    float w0 = csr_w[e0];
        int s1 = (rem > 1) ? csr_src[e0 + 1] : s0; float w1 = (rem > 1) ? csr_w[e0 + 1] : 0.f;
        int s2 = (rem > 2) ? csr_src[e0 + 2] : s0; float w2 = (rem > 2) ? csr_w[e0 + 2] : 0.f;
        int s3 = (rem > 3) ? csr_src[e0 + 3] : s0; float w3 = (rem > 3) ? csr_w[e0 + 3] : 0.f;
        if (kv) {
            float x0 = x[(size_t)s0 * NFEAT + k];
            float x1 = x[(size_t)s1 * NFEAT + k];
            float x2 = x[(size_t)s2 * NFEAT + k];
            float x3 = x[(size_t)s3 * NFEAT + k];
            acc += x0 * w0 + x1 * w1 + x2 * w2 + x3 * w3;
        }
    }
    agg[(size_t)node * 16 + k] = kv ? acc / fmaxf((float)deg, 1.f) : 0.f;
}

// ---------------- Layer-1 dense: x1 = relu(agg@Wrel + x@Wroot + b) ----------------

__global__ __launch_bounds__(256) void k_l1dense(
    const float* __restrict__ x, const float* __restrict__ agg,
    const float* __restrict__ Wrel, const float* __restrict__ brel,
    const float* __restrict__ Wroot, unsigned short* __restrict__ x1b) {
    __shared__ float sWrel[NFEAT][DIM];
    __shared__ float sWroot[NFEAT][DIM];
    __shared__ float sb[DIM];
    int tid = threadIdx.x;
    for (int i = tid; i < NFEAT * DIM; i += 256) {
        (&sWrel[0][0])[i] = Wrel[i];
        (&sWroot[0][0])[i] = Wroot[i];
    }
    if (tid < DIM) sb[tid] = brel[tid];
    __syncthreads();

    int wv = tid >> 6, lane = tid & 63;
    for (int n8 = 0; n8 < 8; ++n8) {
        int node = blockIdx.x * 32 + n8 * 4 + wv;
        // broadcast row loads (all 64 lanes same address)
        float av[NFEAT], xr[NFEAT];
        const float4* ag4 = (const float4*)(agg + (size_t)node * 16);
        float4 a0 = ag4[0], a1 = ag4[1], a2 = ag4[2], a3 = ag4[3];
        av[0]=a0.x; av[1]=a0.y; av[2]=a0.z; av[3]=a0.w;
        av[4]=a1.x; av[5]=a1.y; av[6]=a1.z; av[7]=a1.w;
        av[8]=a2.x; av[9]=a2.y; av[10]=a2.z; av[11]=a2.w;
        av[12]=a3.x; av[13]=a3.y;
        const float2* xr2 = (const float2*)(x + (size_t)node * NFEAT);
#pragma unroll
        for (int k2 = 0; k2 < 7; ++k2) { float2 v = xr2[k2]; xr[2*k2] = v.x; xr[2*k2+1] = v.y; }

#pragma unroll
        for (int j = 0; j < 4; ++j) {
            int d = lane + 64 * j;
            float o = sb[d];
#pragma unroll
            for (int k2 = 0; k2 < NFEAT; ++k2)
                o += av[k2] * sWrel[k2][d] + xr[k2] * sWroot[k2][d];
            x1b[(size_t)node * DIM + d] = f2b(fmaxf(o, 0.f));
        }
    }
}

// ---------------- SpMM mean aggregation (bf16 in/out, fp32 accum, 4-wide MLP) ----------------

__global__ __launch_bounds__(256) void k_spmm_mean(
    const unsigned short* __restrict__ xin, const int* __restrict__ row_ptr,
    const int* __restrict__ cnt, const int* __restrict__ csr_src,
    const float* __restrict__ csr_w, unsigned short* __restrict__ meanb) {
    int wv = threadIdx.x >> 6, lane = threadIdx.x & 63;
    int node = blockIdx.x * 4 + wv;
    int start = row_ptr[node], deg = cnt[node], end = start + deg;
    float a0 = 0.f, a1 = 0.f, a2 = 0.f, a3 = 0.f;
    for (int e0 = start; e0 < end; e0 += 4) {
        int rem = end - e0;
        int s0 = csr_src[e0];                    float w0 = csr_w[e0];
        int s1 = (rem > 1) ? csr_src[e0 + 1] : s0; float w1 = (rem > 1) ? csr_w[e0 + 1] : 0.f;
        int s2 = (rem > 2) ? csr_src[e0 + 2] : s0; float w2 = (rem > 2) ? csr_w[e0 + 2] : 0.f;
        int s3 = (rem > 3) ? csr_src[e0 + 3] : s0; float w3 = (rem > 3) ? csr_w[e0 + 3] : 0.f;
        ushort4 v0 = *(const ushort4*)(xin + (size_t)s0 * DIM + lane * 4);
        ushort4 v1 = *(const ushort4*)(xin + (size_t)s1 * DIM + lane * 4);
        ushort4 v2 = *(const ushort4*)(xin + (size_t)s2 * DIM + lane * 4);
        ushort4 v3 = *(const ushort4*)(xin + (size_t)s3 * DIM + lane * 4);
        a0 += b2f(v0.x) * w0 + b2f(v1.x) * w1 + b2f(v2.x) * w2 + b2f(v3.x) * w3;
        a1 += b2f(v0.y) * w0 + b2f(v1.y) * w1 + b2f(v2.y) * w2 + b2f(v3.y) * w3;
        a2 += b2f(v0.z) * w0 + b2f(v1.z) * w1 + b2f(v2.z) * w2 + b2f(v3.z) * w3;
        a3 += b2f(v0.w) * w0 + b2f(v1.w) * w1 + b2f(v2.w) * w2 + b2f(v3.w) * w3;
    }
    float inv = 1.f / fmaxf((float)deg, 1.f);
    ushort4 o;
    o.x = f2b(a0 * inv); o.y = f2b(a1 * inv); o.z = f2b(a2 * inv); o.w = f2b(a3 * inv);
    *(ushort4*)(meanb + (size_t)node * DIM + lane * 4) = o;
}

// ---------------- bf16 MFMA multi-part GEMM ----------------

__global__ __launch_bounds__(256) void k_gemm_mfma(
    const unsigned short* __restrict__ A0, const unsigned short* __restrict__ A1,
    const unsigned short* __restrict__ A2,
    const unsigned short* __restrict__ B0, const unsigned short* __restrict__ B1,
    const unsigned short* __restrict__ B2,
    int nparts, const float* __restrict__ bias,
    unsigned short* __restrict__ outb, float* __restrict__ outf, int do_relu) {
    __shared__ __align__(16) unsigned short Bs[256][40];
    int t = threadIdx.x;
    int l = t & 63, wv = t >> 6;
    int rowPanel = wv >> 1, colPanel = wv & 1;
    int row0 = blockIdx.x * 32;
    int lr = l & 15, kg = l >> 4;
    int row_a = row0 + rowPanel * 16 + lr;

    f32x4 acc[8];
#pragma unroll
    for (int i = 0; i < 8; i++) acc[i] = (f32x4){0.f, 0.f, 0.f, 0.f};

    for (int p = 0; p < nparts; ++p) {
        const unsigned short* A = (p == 0) ? A0 : (p == 1) ? A1 : A2;
        const unsigned short* B = (p == 0) ? B0 : (p == 1) ? B1 : B2;
        for (int s = 0; s < 8; ++s) {
            const int4* src = (const int4*)(B + (size_t)s * 8192 + (size_t)t * 32);
            int4 v0 = src[0], v1 = src[1], v2 = src[2], v3 = src[3];
            *(int4*)&Bs[t][0]  = v0;
            *(int4*)&Bs[t][8]  = v1;
            *(int4*)&Bs[t][16] = v2;
            *(int4*)&Bs[t][24] = v3;
            __syncthreads();
            bf16x8 a = *(const bf16x8*)(A + (size_t)row_a * DIM + s * 32 + kg * 8);
#pragma unroll
            for (int ct = 0; ct < 8; ++ct) {
                int col = colPanel * 128 + ct * 16 + lr;
                bf16x8 b = *(const bf16x8*)&Bs[col][kg * 8];
                acc[ct] = __builtin_amdgcn_mfma_f32_16x16x32_bf16(a, b, acc[ct], 0, 0, 0);
            }
            __syncthreads();
        }
    }

#pragma unroll
    for (int ct = 0; ct < 8; ++ct) {
        int col = colPanel * 128 + ct * 16 + lr;
        float bv = bias[col];
#pragma unroll
        for (int r = 0; r < 4; ++r) {
            int row = row0 + rowPanel * 16 + kg * 4 + r;
            float v = acc[ct][r] + bv;
            if (do_relu) v = fmaxf(v, 0.f);
            if (outb) outb[(size_t)row * DIM + col] = f2b(v);
            else      outf[(size_t)row * DIM + col] = v;
        }
    }
}

// ---------------- host ----------------

extern "C" void kernel_launch(void* const* d_in, const int* in_sizes, int n_in,
                              void* d_out, int out_size, void* d_ws, size_t ws_size,
                              hipStream_t stream) {
    (void)in_sizes; (void)n_in; (void)out_size; (void)ws_size;
    const float* x       = (const float*)d_in[0];
    const int*   ei      = (const int*)d_in[1];
    const float* ew      = (const float*)d_in[2];
    const float* W1_rel  = (const float*)d_in[3];
    const float* b1      = (const float*)d_in[4];
    const float* W1_root = (const float*)d_in[5];
    const float* W2_rel  = (const float*)d_in[6];
    const float* b2      = (const float*)d_in[7];
    const float* W2_root = (const float*)d_in[8];
    const float* W3_rel  = (const float*)d_in[9];
    const float* b3      = (const float*)d_in[10];
    const float* W3_root = (const float*)d_in[11];
    const float* W_lin   = (const float*)d_in[12];
    const float* b_lin   = (const float*)d_in[13];
    float* out = (float*)d_out;

    char* ws = (char*)d_ws;
    size_t off = 0;
    auto alloc = [&](size_t bytes) -> void* {
        off = (off + 255) & ~(size_t)255;
        void* p = ws + off;
        off += bytes;
        return p;
    };
    int*   cnt     = (int*)alloc((size_t)(N_NODES + 1) * 4);
    int*   row_ptr = (int*)alloc((size_t)N_NODES * 4);
    int*   cursor  = (int*)alloc((size_t)N_NODES * 4);
    int*   csr_src = (int*)alloc((size_t)N_EDGES * 4);
    float* csr_w   = (float*)alloc((size_t)N_EDGES * 4);
    float* agg     = (float*)alloc((size_t)N_NODES * 16 * 4);
    unsigned short* wst   = (unsigned short*)alloc((size_t)7 * 65536 * 2);
    unsigned short* meanb = (unsigned short*)alloc((size_t)N_NODES * DIM * 2);
    unsigned short* x1b   = (unsigned short*)alloc((size_t)N_NODES * DIM * 2);
    unsigned short* x2b   = (unsigned short*)alloc((size_t)N_NODES * DIM * 2);
    unsigned short* x3b   = (unsigned short*)alloc((size_t)N_NODES * DIM * 2);
    int* total = cnt + N_NODES;

    hipMemsetAsync(cnt, 0, (size_t)(N_NODES + 1) * 4, stream);

    int eblocks = (N_EDGES + 255) / 256;
    k_degree<<<eblocks, 256, 0, stream>>>(ei, cnt);
    k_alloc<<<(N_NODES + 255) / 256, 256, 0, stream>>>(cnt, total, row_ptr, cursor);
    k_fill<<<eblocks, 256, 0, stream>>>(ei, ew, cursor, csr_src, csr_w);

    k_wstage<<<56, 256, 0, stream>>>(W2_rel, W2_root, W3_rel, W3_root, W_lin, wst);

    // layer 1: agg (all nodes parallel) then dense
    k_agg14<<<N_NODES * 16 / 256, 256, 0, stream>>>(x, row_ptr, cnt, csr_src, csr_w, agg);
    k_l1dense<<<N_NODES / 32, 256, 0, stream>>>(x, agg, W1_rel, b1, W1_root, x1b);

    const int ggrid = N_NODES / 32;   // 625

    // layer 2
    k_spmm_mean<<<N_NODES / 4, 256, 0, stream>>>(x1b, row_ptr, cnt, csr_src, csr_w, meanb);
    k_gemm_mfma<<<ggrid, 256, 0, stream>>>(meanb, x1b, nullptr,
                                           wst, wst + 65536, nullptr,
                                           2, b2, x2b, nullptr, 1);

    // layer 3
    k_spmm_mean<<<N_NODES / 4, 256, 0, stream>>>(x2b, row_ptr, cnt, csr_src, csr_w, meanb);
    k_gemm_mfma<<<ggrid, 256, 0, stream>>>(meanb, x2b, nullptr,
                                           wst + 2 * 65536, wst + 3 * 65536, nullptr,
                                           2, b3, x3b, nullptr, 1);

    // final: concat(x1,x2,x3) @ W_lin + b_lin -> fp32 out
    k_gemm_mfma<<<ggrid, 256, 0, stream>>>(x1b, x2b, x3b,
                                           wst + 4 * 65536, wst + 5 * 65536, wst + 6 * 65536,
                                           3, b_lin, nullptr, out, 0);
}